// Round 3
// baseline (924.386 us; speedup 1.0000x reference)
//
#include <hip/hip_runtime.h>
#include <math.h>

#define BIGF 1e10f
#define EPSF 1e-5f

// ---------------------------------------------------------------------------
// Prepack: fold BN into conv weights + biases (unchanged layouts)
//   wp3: [layer4][ocg8][ic64][ocL8][tap9]   wp1: [ocg8][ic3][tap49][ocL8]
// ---------------------------------------------------------------------------
__global__ __launch_bounds__(256) void prepack(
    const float* __restrict__ c1w,
    const float* __restrict__ bn1g, const float* __restrict__ bn1b,
    const float* __restrict__ bn1m, const float* __restrict__ bn1v,
    const float* __restrict__ blkw,
    const float* __restrict__ blkg, const float* __restrict__ blkb,
    const float* __restrict__ blkm, const float* __restrict__ blkv,
    float* __restrict__ wp3, float* __restrict__ wp1,
    float* __restrict__ b3, float* __restrict__ b1)
{
    int idx = blockIdx.x * 256 + threadIdx.x;
    if (idx < 147456) {
        int tap = idx % 9; int r = idx / 9;
        int ocL = r % 8; r >>= 3;
        int ic  = r % 64; r >>= 6;
        int ocg = r % 8; int layer = r >> 3;
        int oc = ocg * 8 + ocL;
        float s = blkg[layer * 64 + oc] * rsqrtf(blkv[layer * 64 + oc] + EPSF);
        wp3[idx] = blkw[(((size_t)layer * 64 + oc) * 64 + ic) * 9 + tap] * s;
    }
    int j = idx - 147456;
    if (j >= 0 && j < 9408) {
        int ocL = j % 8; int r = j / 8;
        int tap = r % 49; r /= 49;
        int ic  = r % 3;  int ocg = r / 3;
        int oc = ocg * 8 + ocL;
        float s = bn1g[oc] * rsqrtf(bn1v[oc] + EPSF);
        wp1[j] = c1w[((size_t)oc * 3 + ic) * 49 + tap] * s;
    }
    int k = idx - 147456 - 9408;
    if (k >= 0 && k < 256) {
        float s = blkg[k] * rsqrtf(blkv[k] + EPSF);
        b3[k] = blkb[k] - blkm[k] * s;
    }
    int l = idx - 147456 - 9408 - 256;
    if (l >= 0 && l < 64) {
        float s = bn1g[l] * rsqrtf(bn1v[l] + EPSF);
        b1[l] = bn1b[l] - bn1m[l] * s;
    }
}

// ---------------------------------------------------------------------------
// Kernel 1: conv1 7x7 s2 p3 + foldedBN + ReLU + maxpool, 3 row-strips.
// 3072 blocks = strip(3) x ocg(8) x b(128), 576 threads.
// Strip s: conv rows base=15*s+{0..17}? -> bases {0,15,30}, 18 conv rows,
// pool rows 8s..8s+7. LDS: padded input rows [41][102] = 16.7 KB.
// ---------------------------------------------------------------------------
__global__ __launch_bounds__(576) void conv1_pool(
    const float* __restrict__ x, const float* __restrict__ wp1,
    const float* __restrict__ bias, float* __restrict__ out)
{
    __shared__ float plane[41 * 102];
    const int bid = blockIdx.x;
    const int b = bid & 127;
    const int ocg = (bid >> 7) & 7;
    const int strip = bid >> 10;            // 0..2
    const int tid = threadIdx.x;

    const int base = strip * 15;            // first conv row of strip
    const int Ri = base * 2 - 3;            // first padded input row held
    const int r0g = (Ri < 0) ? 0 : Ri;      // first valid global row
    const int r1g = (Ri + 40 > 95) ? 95 : Ri + 40;
    const int nInt = (r1g - r0g + 1) * 96;  // interior element count

    // zero whole plane once (halo stays zero)
    for (int k = tid; k < 41 * 102; k += 576) plane[k] = 0.f;

    // px assignment: 18*48=864 conv px; px1 = tid, px2 = 576+tid (tid<288)
    const int lr1 = tid / 48, cc1 = tid % 48;
    const int p2 = 576 + tid;
    const int lr2 = p2 / 48, cc2 = p2 % 48;
    const bool hasP2 = (tid < 288);
    const int off1 = lr1 * 2 * 102 + cc1 * 2;
    const int off2 = lr2 * 2 * 102 + cc2 * 2;

    float acc[2][8];
#pragma unroll
    for (int j = 0; j < 2; ++j)
#pragma unroll
        for (int t = 0; t < 8; ++t) acc[j][t] = 0.f;

    const float* xb = x + (size_t)b * 3 * 9216;
    const int planeBase = (r0g - Ri) * 102 + 3;

    // preload ic 0
    float rv[7];
#pragma unroll
    for (int i = 0; i < 7; ++i) {
        int k = tid + i * 576;
        rv[i] = (k < nInt) ? xb[(size_t)r0g * 96 + k] : 0.f;
    }

    for (int ic = 0; ic < 3; ++ic) {
        __syncthreads();
#pragma unroll
        for (int i = 0; i < 7; ++i) {
            int k = tid + i * 576;
            if (k < nInt) plane[planeBase + (k / 96) * 102 + (k % 96)] = rv[i];
        }
        __syncthreads();
        // prefetch next ic (clamped -> last iter reloads ic2 harmlessly)
        const int icn = (ic < 2) ? ic + 1 : 2;
        const float* xn = xb + (size_t)icn * 9216;
        float rn[7];
#pragma unroll
        for (int i = 0; i < 7; ++i) {
            int k = tid + i * 576;
            rn[i] = (k < nInt) ? xn[(size_t)r0g * 96 + k] : 0.f;
        }

        const float* wq = wp1 + ((size_t)ocg * 3 + ic) * 392;
#pragma unroll 1
        for (int kh = 0; kh < 7; ++kh) {
#pragma unroll
            for (int kw = 0; kw < 7; ++kw) {
                const float* wt = wq + (kh * 7 + kw) * 8;
                float w0 = wt[0], w1 = wt[1], w2 = wt[2], w3 = wt[3];
                float w4 = wt[4], w5 = wt[5], w6 = wt[6], w7 = wt[7];
                float v1 = plane[off1 + kh * 102 + kw];
                acc[0][0] = fmaf(v1, w0, acc[0][0]);
                acc[0][1] = fmaf(v1, w1, acc[0][1]);
                acc[0][2] = fmaf(v1, w2, acc[0][2]);
                acc[0][3] = fmaf(v1, w3, acc[0][3]);
                acc[0][4] = fmaf(v1, w4, acc[0][4]);
                acc[0][5] = fmaf(v1, w5, acc[0][5]);
                acc[0][6] = fmaf(v1, w6, acc[0][6]);
                acc[0][7] = fmaf(v1, w7, acc[0][7]);
                if (hasP2) {
                    float v2 = plane[off2 + kh * 102 + kw];
                    acc[1][0] = fmaf(v2, w0, acc[1][0]);
                    acc[1][1] = fmaf(v2, w1, acc[1][1]);
                    acc[1][2] = fmaf(v2, w2, acc[1][2]);
                    acc[1][3] = fmaf(v2, w3, acc[1][3]);
                    acc[1][4] = fmaf(v2, w4, acc[1][4]);
                    acc[1][5] = fmaf(v2, w5, acc[1][5]);
                    acc[1][6] = fmaf(v2, w6, acc[1][6]);
                    acc[1][7] = fmaf(v2, w7, acc[1][7]);
                }
            }
        }
#pragma unroll
        for (int i = 0; i < 7; ++i) rv[i] = rn[i];
    }

    // pool: per oc, relu conv vals -> LDS[0..863], then 8x24 pooled outputs
    const int prL = tid / 24, pc = tid % 24;        // tid<192: pool px
    float* op = out + ((size_t)b * 64 + ocg * 8) * 576;
#pragma unroll
    for (int t = 0; t < 8; ++t) {
        float bi = bias[ocg * 8 + t];
        __syncthreads();
        plane[tid] = fmaxf(acc[0][t] + bi, 0.f);
        if (hasP2) plane[p2] = fmaxf(acc[1][t] + bi, 0.f);
        __syncthreads();
        if (tid < 192) {
            int prAbs = strip * 8 + prL;
            int lcr0 = prAbs * 2 - 1 - base;        // local conv row of kr=0
            float m = -INFINITY;
#pragma unroll
            for (int kr = 0; kr < 3; ++kr) {
                int lr = lcr0 + kr;
                if (lr < 0 || lr > 17) continue;
                int iw0 = pc * 2 - 1;
#pragma unroll
                for (int kw = 0; kw < 3; ++kw) {
                    int iw = iw0 + kw;
                    if (iw < 0 || iw >= 48) continue;
                    m = fmaxf(m, plane[lr * 48 + iw]);
                }
            }
            op[t * 576 + prAbs * 24 + pc] = m;
        }
    }
}

// ---------------------------------------------------------------------------
// Kernel 2: conv3x3 + foldedBN (+res) + ReLU. ic-chunk = 4 (LDS 10.8 KB ->
// 3 blocks/CU), reg-staged prefetch of next chunk.
// ---------------------------------------------------------------------------
template<int MODE>
__global__ __launch_bounds__(576) void conv3_bn(
    const float* __restrict__ in,       // [128,64,24,24]
    const float* __restrict__ wp,       // [8 ocg][64 ic][8 oc][9] folded
    const float* __restrict__ bias,     // [64] folded
    const float* __restrict__ res,      // MODE==1 only
    float* __restrict__ out)
{
    __shared__ float plane[4 * 676];    // 4 ic, padded 26x26
    const int bid = blockIdx.x;
    const int ocg = bid >> 7, b = bid & 127;
    const int tid = threadIdx.x;        // = r*24 + c
    const int ohw = (tid / 24 + 1) * 26 + (tid % 24 + 1);

    float acc[8] = {0.f, 0.f, 0.f, 0.f, 0.f, 0.f, 0.f, 0.f};

    for (int k = tid; k < 4 * 676; k += 576) plane[k] = 0.f;

    const float* inb = in + (size_t)b * (64 * 576);
    const float* wg  = wp + (size_t)ocg * (64 * 72);

    float rv[4];
#pragma unroll
    for (int i = 0; i < 4; ++i) rv[i] = inb[i * 576 + tid];

    for (int c0 = 0; c0 < 64; c0 += 4) {
        __syncthreads();
#pragma unroll
        for (int i = 0; i < 4; ++i) plane[i * 676 + ohw] = rv[i];
        __syncthreads();
        const int nc = (c0 + 4 < 60) ? c0 + 4 : 60;   // clamped prefetch
        float rn[4];
#pragma unroll
        for (int i = 0; i < 4; ++i) rn[i] = inb[(nc + i) * 576 + tid];

#pragma unroll
        for (int icL = 0; icL < 4; ++icL) {
            const float* pp = &plane[icL * 676 + ohw - 27];
            float v0 = pp[0],  v1 = pp[1],  v2 = pp[2];
            float v3 = pp[26], v4 = pp[27], v5 = pp[28];
            float v6 = pp[52], v7 = pp[53], v8 = pp[54];
            const float* wq = wg + (c0 + icL) * 72;
#pragma unroll
            for (int t = 0; t < 8; ++t) {
                const float* wt = wq + t * 9;
                float a = acc[t];
                a = fmaf(v0, wt[0], a);
                a = fmaf(v1, wt[1], a);
                a = fmaf(v2, wt[2], a);
                a = fmaf(v3, wt[3], a);
                a = fmaf(v4, wt[4], a);
                a = fmaf(v5, wt[5], a);
                a = fmaf(v6, wt[6], a);
                a = fmaf(v7, wt[7], a);
                a = fmaf(v8, wt[8], a);
                acc[t] = a;
            }
        }
#pragma unroll
        for (int i = 0; i < 4; ++i) rv[i] = rn[i];
    }

#pragma unroll
    for (int t = 0; t < 8; ++t) {
        const int oc = ocg * 8 + t;
        float v = acc[t] + bias[oc];
        size_t oidx = ((size_t)b * 64 + oc) * 576 + tid;
        if (MODE == 1) v += res[oidx];
        out[oidx] = fmaxf(v, 0.f);
    }
}

// ---------------------------------------------------------------------------
// Kernel 3: FC split-K GEMM, float4 staging loads.
// ---------------------------------------------------------------------------
#define KSPLIT 36
#define KCHUNK 1024

__global__ __launch_bounds__(256) void fc_splitk(
    const float* __restrict__ A,   // [128, 36864]
    const float* __restrict__ B,   // [144, 36864]
    float* __restrict__ part)      // [36][128*144]
{
    __shared__ float As[32][33];
    __shared__ float Bs[48][33];
    const int mBase = blockIdx.x * 32;
    const int nBase = blockIdx.y * 48;
    const int s = blockIdx.z;
    const int t = threadIdx.x;
    const int mIdx = t >> 4, nIdx = t & 15;

    float acc[2][3] = {{0.f,0.f,0.f},{0.f,0.f,0.f}};

    const int k0 = s * KCHUNK;
    for (int kk = k0; kk < k0 + KCHUNK; kk += 32) {
        __syncthreads();
        {
            int r = t >> 3, f = (t & 7) * 4;
            float4 va = *(const float4*)&A[(size_t)(mBase + r) * 36864 + kk + f];
            As[r][f] = va.x; As[r][f+1] = va.y; As[r][f+2] = va.z; As[r][f+3] = va.w;
            int li = t + 256;
            if (li < 384 + 256) {} // keep structure simple
        }
#pragma unroll
        for (int i = 0; i < 2; ++i) {
            int li = t + i * 256;
            if (li < 384) {
                int r = li >> 3, f = (li & 7) * 4;
                float4 vb = *(const float4*)&B[(size_t)(nBase + r) * 36864 + kk + f];
                Bs[r][f] = vb.x; Bs[r][f+1] = vb.y; Bs[r][f+2] = vb.z; Bs[r][f+3] = vb.w;
            }
        }
        __syncthreads();
#pragma unroll
        for (int k = 0; k < 32; ++k) {
            float a0 = As[mIdx][k], a1 = As[mIdx + 16][k];
            float b0 = Bs[nIdx][k], b1 = Bs[nIdx + 16][k], b2 = Bs[nIdx + 32][k];
            acc[0][0] = fmaf(a0, b0, acc[0][0]);
            acc[0][1] = fmaf(a0, b1, acc[0][1]);
            acc[0][2] = fmaf(a0, b2, acc[0][2]);
            acc[1][0] = fmaf(a1, b0, acc[1][0]);
            acc[1][1] = fmaf(a1, b1, acc[1][1]);
            acc[1][2] = fmaf(a1, b2, acc[1][2]);
        }
    }
    float* pp = part + (size_t)s * (128 * 144);
#pragma unroll
    for (int i = 0; i < 2; ++i)
#pragma unroll
        for (int j = 0; j < 3; ++j)
            pp[(size_t)(mBase + mIdx + i * 16) * 144 + nBase + nIdx + j * 16] = acc[i][j];
}

__global__ __launch_bounds__(256) void fc_reduce(
    const float* __restrict__ part, const float* __restrict__ bias,
    float* __restrict__ costs)
{
    int idx = blockIdx.x * 256 + threadIdx.x;
    if (idx >= 128 * 144) return;
    float sum = bias[idx % 144];
    for (int s = 0; s < KSPLIT; ++s) sum += part[(size_t)s * (128 * 144) + idx];
    costs[idx] = sum;
}

// ---------------------------------------------------------------------------
// Kernel 4: Bellman-Ford (144 iters) + greedy backtrack (unchanged)
// ---------------------------------------------------------------------------
__global__ __launch_bounds__(192) void shortest_path(
    const float* __restrict__ costs, float* __restrict__ out)
{
    __shared__ float dA[144], dB[144], cs[144], mask[144];
    const int b = blockIdx.x, tid = threadIdx.x;
    if (tid < 144) {
        float c = costs[b * 144 + tid];
        cs[tid] = c;
        dA[tid] = (tid == 0) ? c : BIGF;
        mask[tid] = 0.f;
    }
    __syncthreads();
    float* cur = dA; float* nxt = dB;
    for (int it = 0; it < 144; ++it) {
        if (tid < 144) {
            int i = tid / 12, j = tid % 12;
            float up = (i > 0)  ? cur[tid - 12] : BIGF;
            float dn = (i < 11) ? cur[tid + 12] : BIGF;
            float lf = (j > 0)  ? cur[tid - 1]  : BIGF;
            float rt = (j < 11) ? cur[tid + 1]  : BIGF;
            float nb = fminf(fminf(up, dn), fminf(lf, rt));
            nxt[tid] = fminf(cur[tid], nb + cs[tid]);
        }
        __syncthreads();
        float* tp = cur; cur = nxt; nxt = tp;
    }
    if (tid == 0) {
        int i = 11, j = 11;
        const int di[4] = {-1, 1, 0, 0};
        const int dj[4] = {0, 0, -1, 1};
        for (int it = 0; it < 144; ++it) {
            mask[i * 12 + j] = 1.f;
            float vals[4];
#pragma unroll
            for (int k = 0; k < 4; ++k) {
                int ni = i + di[k], nj = j + dj[k];
                bool valid = (ni >= 0) && (ni < 12) && (nj >= 0) && (nj < 12);
                vals[k] = valid ? cur[ni * 12 + nj] : BIGF;
            }
            float best = vals[0]; int kb = 0;
#pragma unroll
            for (int k = 1; k < 4; ++k)
                if (vals[k] < best) { best = vals[k]; kb = k; }
            if (!(i == 0 && j == 0)) { i += di[kb]; j += dj[kb]; }
        }
    }
    __syncthreads();
    if (tid < 144) out[b * 144 + tid] = mask[tid];
}

// ---------------------------------------------------------------------------
extern "C" void kernel_launch(void* const* d_in, const int* in_sizes, int n_in,
                              void* d_out, int out_size, void* d_ws, size_t ws_size,
                              hipStream_t stream) {
    const float* x    = (const float*)d_in[0];
    const float* c1w  = (const float*)d_in[1];
    const float* bn1g = (const float*)d_in[2];
    const float* bn1b = (const float*)d_in[3];
    const float* bn1m = (const float*)d_in[4];
    const float* bn1v = (const float*)d_in[5];
    const float* blkw = (const float*)d_in[6];
    const float* blkg = (const float*)d_in[7];
    const float* blkb = (const float*)d_in[8];
    const float* blkm = (const float*)d_in[9];
    const float* blkv = (const float*)d_in[10];
    const float* fcw  = (const float*)d_in[11];
    const float* fcb  = (const float*)d_in[12];
    float* out = (float*)d_out;
    float* ws  = (float*)d_ws;

    const size_t ACT = 4718592;              // 128*64*24*24
    float* hp    = ws;
    float* t1    = ws + ACT;
    float* h2    = ws + 2 * ACT;
    float* costs = ws + 3 * ACT;             // 18432
    float* part  = costs + 18432;            // 36*18432 floats
    // packed weights overlap `part` (dead until FC; convs done by then)
    float* wp3 = part;                       // 147456
    float* wp1 = wp3 + 147456;               // 9408
    float* b3  = wp1 + 9408;                 // 256
    float* b1  = b3 + 256;                   // 64

    prepack<<<dim3(614), dim3(256), 0, stream>>>(
        c1w, bn1g, bn1b, bn1m, bn1v, blkw, blkg, blkb, blkm, blkv,
        wp3, wp1, b3, b1);

    conv1_pool<<<dim3(3072), dim3(576), 0, stream>>>(x, wp1, b1, hp);

    conv3_bn<0><<<dim3(1024), dim3(576), 0, stream>>>(
        hp, wp3 + 0 * 36864, b3 + 0,   nullptr, t1);
    conv3_bn<1><<<dim3(1024), dim3(576), 0, stream>>>(
        t1, wp3 + 1 * 36864, b3 + 64,  hp, h2);
    conv3_bn<0><<<dim3(1024), dim3(576), 0, stream>>>(
        h2, wp3 + 2 * 36864, b3 + 128, nullptr, t1);
    conv3_bn<1><<<dim3(1024), dim3(576), 0, stream>>>(
        t1, wp3 + 3 * 36864, b3 + 192, h2, hp);

    fc_splitk<<<dim3(4, 3, 36), dim3(256), 0, stream>>>(hp, fcw, part);
    fc_reduce<<<dim3(72), dim3(256), 0, stream>>>(part, fcb, costs);
    shortest_path<<<dim3(128), dim3(192), 0, stream>>>(costs, out);
}

// Round 5
// 326.969 us; speedup vs baseline: 2.8271x; 2.8271x over previous
//
#include <hip/hip_runtime.h>
#include <math.h>

#define BIGF 1e10f
#define EPSF 1e-5f

typedef _Float16 f16;
typedef f16 f16x8 __attribute__((ext_vector_type(8)));
typedef float f32x4 __attribute__((ext_vector_type(4)));

// ---------------------------------------------------------------------------
// Prepack: fold BN; build conv1 packed weights (fp32) and conv3 MFMA B-frags
// (f16 hi/lo) in layout [layer4][tap9][ntile4][kf2][hl2][lane64][j8].
// ---------------------------------------------------------------------------
__global__ __launch_bounds__(256) void prepack(
    const float* __restrict__ c1w,
    const float* __restrict__ bn1g, const float* __restrict__ bn1b,
    const float* __restrict__ bn1m, const float* __restrict__ bn1v,
    const float* __restrict__ blkw,
    const float* __restrict__ blkg, const float* __restrict__ blkb,
    const float* __restrict__ blkm, const float* __restrict__ blkv,
    f16* __restrict__ wB, float* __restrict__ wp1,
    float* __restrict__ b3, float* __restrict__ b1)
{
    int idx = blockIdx.x * 256 + threadIdx.x;
    if (idx < 147456) {                    // conv3 weight frags
        int pos = idx;
        int j    = pos & 7;
        int lane = (pos >> 3) & 63;
        int rest = pos >> 9;               // (((layer*9+tap)*4+nt)*2+kf)
        int kf   = rest & 1;
        int r2   = rest >> 1;
        int ntl  = r2 & 3;
        int r3   = r2 >> 2;
        int tap  = r3 % 9;
        int layer= r3 / 9;
        int ic = kf * 32 + (lane >> 4) * 8 + j;
        int oc = ntl * 16 + (lane & 15);
        float s = blkg[layer * 64 + oc] * rsqrtf(blkv[layer * 64 + oc] + EPSF);
        float wv = blkw[(((size_t)layer * 64 + oc) * 64 + ic) * 9 + tap] * s;
        f16 h = (f16)wv;
        f16 lo = (f16)(wv - (float)h);
        int low9 = pos & 511;
        wB[(size_t)rest * 1024 + low9]       = h;
        wB[(size_t)rest * 1024 + 512 + low9] = lo;
    }
    int jj = idx - 147456;
    if (jj >= 0 && jj < 9408) {            // conv1 weights [ocg][ic][tap][ocL]
        int ocL = jj % 8; int r = jj / 8;
        int tap = r % 49; r /= 49;
        int ic  = r % 3;  int ocg = r / 3;
        int oc = ocg * 8 + ocL;
        float s = bn1g[oc] * rsqrtf(bn1v[oc] + EPSF);
        wp1[jj] = c1w[((size_t)oc * 3 + ic) * 49 + tap] * s;
    }
    int k = idx - 147456 - 9408;
    if (k >= 0 && k < 256) {
        float s = blkg[k] * rsqrtf(blkv[k] + EPSF);
        b3[k] = blkb[k] - blkm[k] * s;
    }
    int l = idx - 147456 - 9408 - 256;
    if (l >= 0 && l < 64) {
        float s = bn1g[l] * rsqrtf(bn1v[l] + EPSF);
        b1[l] = bn1b[l] - bn1m[l] * s;
    }
}

// ---------------------------------------------------------------------------
// conv1 7x7 s2 p3 + foldedBN + ReLU + maxpool (fp32 VALU, R2-proven core),
// epilogue writes NHWC f16 hi/lo. 1024 blocks, 576 threads.
// ---------------------------------------------------------------------------
__global__ __launch_bounds__(576) void conv1_pool(
    const float* __restrict__ x, const float* __restrict__ wp1,
    const float* __restrict__ bias, f16* __restrict__ outh, f16* __restrict__ outl)
{
    __shared__ float plane[102 * 102];
    const int bid = blockIdx.x;
    const int ocg = bid >> 7, b = bid & 127;
    const int tid = threadIdx.x;

    float acc[4][8];
#pragma unroll
    for (int j = 0; j < 4; ++j)
#pragma unroll
        for (int t = 0; t < 8; ++t) acc[j][t] = 0.f;

    int offp[4];
#pragma unroll
    for (int j = 0; j < 4; ++j) {
        int px = tid + 576 * j;
        offp[j] = (px / 48) * 2 * 102 + (px % 48) * 2;
    }

    for (int k = tid; k < 102 * 102; k += 576) plane[k] = 0.f;

    const float* xb = x + (size_t)b * 3 * 9216;
    for (int ic = 0; ic < 3; ++ic) {
        __syncthreads();
#pragma unroll
        for (int k = 0; k < 16; ++k) {
            int p = tid + 576 * k;
            plane[(p / 96 + 3) * 102 + (p % 96) + 3] = xb[ic * 9216 + p];
        }
        __syncthreads();
        const float* wq = wp1 + ((size_t)ocg * 3 + ic) * 392;
#pragma unroll 1
        for (int kh = 0; kh < 7; ++kh) {
#pragma unroll
            for (int kw = 0; kw < 7; ++kw) {
                const float* wt = wq + (kh * 7 + kw) * 8;
                float w0 = wt[0], w1 = wt[1], w2 = wt[2], w3 = wt[3];
                float w4 = wt[4], w5 = wt[5], w6 = wt[6], w7 = wt[7];
#pragma unroll
                for (int j = 0; j < 4; ++j) {
                    float v = plane[offp[j] + kh * 102 + kw];
                    acc[j][0] = fmaf(v, w0, acc[j][0]);
                    acc[j][1] = fmaf(v, w1, acc[j][1]);
                    acc[j][2] = fmaf(v, w2, acc[j][2]);
                    acc[j][3] = fmaf(v, w3, acc[j][3]);
                    acc[j][4] = fmaf(v, w4, acc[j][4]);
                    acc[j][5] = fmaf(v, w5, acc[j][5]);
                    acc[j][6] = fmaf(v, w6, acc[j][6]);
                    acc[j][7] = fmaf(v, w7, acc[j][7]);
                }
            }
        }
    }

    const int ph = tid / 24, pw = tid % 24;
    float mv[8];
#pragma unroll
    for (int t = 0; t < 8; ++t) {
        float bi = bias[ocg * 8 + t];
        __syncthreads();
#pragma unroll
        for (int j = 0; j < 4; ++j)
            plane[tid + 576 * j] = fmaxf(acc[j][t] + bi, 0.f);
        __syncthreads();
        float m = -INFINITY;
        int ih0 = ph * 2 - 1, iw0 = pw * 2 - 1;
#pragma unroll
        for (int kh = 0; kh < 3; ++kh) {
            int ih = ih0 + kh;
            if (ih < 0 || ih >= 48) continue;
#pragma unroll
            for (int kw = 0; kw < 3; ++kw) {
                int iw = iw0 + kw;
                if (iw < 0 || iw >= 48) continue;
                m = fmaxf(m, plane[ih * 48 + iw]);
            }
        }
        mv[t] = m;
    }
    f16x8 vh, vl;
#pragma unroll
    for (int t = 0; t < 8; ++t) {
        f16 h = (f16)mv[t];
        vh[t] = h;
        vl[t] = (f16)(mv[t] - (float)h);
    }
    size_t base = (size_t)b * 36864 + (size_t)tid * 64 + ocg * 8;
    *(f16x8*)&outh[base] = vh;
    *(f16x8*)&outl[base] = vl;
}

// ---------------------------------------------------------------------------
// conv3x3 s1 p1 (64->64) + foldedBN (+res) + ReLU via f16-split MFMA.
// Block = (row-group of 8 rows, image): grid (3,128), 256 thr (4 waves).
// Wave w: M-tiles {3w..3w+2} (48 px) x all 4 N-tiles (64 oc).
// A staged once in XOR-swizzled LDS (hi+lo); B frags straight from global.
// OUTT=0: NHWC h/l out; OUTT=1: NCHW-transposed h/l out (feeds FC).
// ---------------------------------------------------------------------------
template<int MODE, int OUTT>
__global__ __launch_bounds__(256) void conv3_mfma(
    const f16* __restrict__ inh, const f16* __restrict__ inl,
    const f16* __restrict__ wB,      // this layer's frag base (73728 halves)
    const float* __restrict__ bias,  // folded [64]
    const f16* __restrict__ resh, const f16* __restrict__ resl,
    f16* __restrict__ outh, f16* __restrict__ outl)
{
    __shared__ f16 lh[10 * 26 * 64];
    __shared__ f16 ll[10 * 26 * 64];
    const int r0 = blockIdx.x * 8;
    const int b  = blockIdx.y;
    const int tid = threadIdx.x;
    const int w = tid >> 6, l = tid & 63;
    const int l15 = l & 15, lg = l >> 4;

    // zero border cols (pc = 0, 25)
    for (int i = tid; i < 320; i += 256) {
        int arr = i >= 160; int c2 = i - arr * 160;
        int slot = c2 & 7; int pb = c2 >> 3;          // 0..19
        int lr = pb >> 1; int pc = (pb & 1) ? 25 : 0;
        int pix = lr * 26 + pc;
        int off = (pix * 128 + slot * 16) ^ ((pix & 7) << 4);
        *(uint4*)((arr ? (char*)ll : (char*)lh) + off) = make_uint4(0, 0, 0, 0);
    }
    // interior staging: 3840 16B-chunks (2 arrays x 10 rows x 24 cols x 8 slots)
#pragma unroll
    for (int i = 0; i < 15; ++i) {
        int ch = tid + i * 256;
        int arr = ch >= 1920; int c2 = ch - arr * 1920;
        int slot = c2 & 7; int pix24 = c2 >> 3;        // 0..239
        int lr = pix24 / 24, pc = pix24 % 24;
        int ir = r0 - 1 + lr;
        uint4 v = make_uint4(0, 0, 0, 0);
        if ((unsigned)ir < 24u) {
            const f16* src = (arr ? inl : inh) +
                (((size_t)b * 576 + ir * 24 + pc) << 6) + slot * 8;
            v = *(const uint4*)(const void*)src;
        }
        int pix = lr * 26 + pc + 1;
        int off = (pix * 128 + slot * 16) ^ ((pix & 7) << 4);
        *(uint4*)((arr ? (char*)ll : (char*)lh) + off) = v;
    }

    int pr_[3], pc_[3];
#pragma unroll
    for (int mtl = 0; mtl < 3; ++mtl) {
        int lp = (w * 3 + mtl) * 16 + l15;
        pr_[mtl] = lp / 24; pc_[mtl] = lp % 24;
    }

    f32x4 acc[3][4];
#pragma unroll
    for (int m = 0; m < 3; ++m)
#pragma unroll
        for (int n = 0; n < 4; ++n) acc[m][n] = (f32x4){0.f, 0.f, 0.f, 0.f};

    __syncthreads();

#pragma unroll 1
    for (int tap = 0; tap < 9; ++tap) {
        int dr = tap / 3, dc = tap % 3;                // offsets 0..2 (pad folded)
#pragma unroll
        for (int kf = 0; kf < 2; ++kf) {
            // layout stride: tap=8192, nt=2048, kf=1024, hl=512 halves
            const f16* wb = wB + (size_t)tap * 8192 + (size_t)kf * 1024 + (size_t)l * 8;
            f16x8 bh[4], bl[4];
#pragma unroll
            for (int nt = 0; nt < 4; ++nt) {
                bh[nt] = *(const f16x8*)(const void*)(wb + nt * 2048);
                bl[nt] = *(const f16x8*)(const void*)(wb + nt * 2048 + 512);
            }
#pragma unroll
            for (int mtl = 0; mtl < 3; ++mtl) {
                int pix = (pr_[mtl] + dr) * 26 + (pc_[mtl] + dc);
                int off = (pix * 128 + kf * 64 + lg * 16) ^ ((pix & 7) << 4);
                f16x8 ah = *(const f16x8*)((const char*)lh + off);
                f16x8 al = *(const f16x8*)((const char*)ll + off);
#pragma unroll
                for (int nt = 0; nt < 4; ++nt) {
                    acc[mtl][nt] = __builtin_amdgcn_mfma_f32_16x16x32_f16(ah, bh[nt], acc[mtl][nt], 0, 0, 0);
                    acc[mtl][nt] = __builtin_amdgcn_mfma_f32_16x16x32_f16(ah, bl[nt], acc[mtl][nt], 0, 0, 0);
                    acc[mtl][nt] = __builtin_amdgcn_mfma_f32_16x16x32_f16(al, bh[nt], acc[mtl][nt], 0, 0, 0);
                }
            }
        }
    }

    float bi[4];
#pragma unroll
    for (int nt = 0; nt < 4; ++nt) bi[nt] = bias[nt * 16 + l15];

#pragma unroll
    for (int mtl = 0; mtl < 3; ++mtl) {
#pragma unroll
        for (int nt = 0; nt < 4; ++nt) {
#pragma unroll
            for (int r = 0; r < 4; ++r) {
                int lp = (w * 3 + mtl) * 16 + lg * 4 + r;
                int p = r0 * 24 + lp;                   // pixel 0..575
                int oc = nt * 16 + l15;
                float v = acc[mtl][nt][r] + bi[nt];
                if (MODE) {
                    size_t ridx = (size_t)b * 36864 + (size_t)p * 64 + oc;
                    v += (float)resh[ridx] + (float)resl[ridx];
                }
                v = fmaxf(v, 0.f);
                f16 h = (f16)v;
                f16 lo = (f16)(v - (float)h);
                size_t oidx = OUTT ? ((size_t)b * 36864 + (size_t)oc * 576 + p)
                                   : ((size_t)b * 36864 + (size_t)p * 64 + oc);
                outh[oidx] = h;
                outl[oidx] = lo;
            }
        }
    }
}

// ---------------------------------------------------------------------------
// FC via f16-split MFMA. A = actT (NCHW h/l, [128][36864] in fcw-native k),
// B = fcw fp32 (split at staging). Grid (9 ntiles, 32 ksplits), 256 thr.
// ---------------------------------------------------------------------------
#define FC_KSPLIT 32

__global__ __launch_bounds__(256) void fc_mfma(
    const f16* __restrict__ Ath, const f16* __restrict__ Atl,
    const float* __restrict__ Bw, float* __restrict__ part)
{
    __shared__ f16 As[2][128 * 40];
    __shared__ f16 Bs[2][16 * 40];
    const int nt = blockIdx.x;        // 0..8
    const int ks = blockIdx.y;        // 0..31
    const int tid = threadIdx.x;
    const int w = tid >> 6, l = tid & 63;
    const int l15 = l & 15, lg = l >> 4;
    const int k0b = ks * 1152;

    f32x4 acc[2];
    acc[0] = (f32x4){0.f, 0.f, 0.f, 0.f};
    acc[1] = (f32x4){0.f, 0.f, 0.f, 0.f};

    const int bn = tid >> 4, bkl = (tid & 15) * 2;
#pragma unroll 1
    for (int st = 0; st < 36; ++st) {
        int k0 = k0b + st * 32;
        __syncthreads();
#pragma unroll
        for (int i = 0; i < 4; ++i) {
            int ch = tid + i * 256;
            int arr = ch >= 512; int c2 = ch - arr * 512;
            int m = c2 >> 2, slot = c2 & 3;
            const f16* src = (arr ? Atl : Ath) + (size_t)m * 36864 + k0 + slot * 8;
            *(uint4*)(void*)&As[arr][m * 40 + slot * 8] = *(const uint4*)(const void*)src;
        }
        {
            float2 f2 = *(const float2*)&Bw[(size_t)(nt * 16 + bn) * 36864 + k0 + bkl];
            f16 h0 = (f16)f2.x, h1 = (f16)f2.y;
            Bs[0][bn * 40 + bkl] = h0;     Bs[0][bn * 40 + bkl + 1] = h1;
            Bs[1][bn * 40 + bkl] = (f16)(f2.x - (float)h0);
            Bs[1][bn * 40 + bkl + 1] = (f16)(f2.y - (float)h1);
        }
        __syncthreads();
        f16x8 bh = *(const f16x8*)(const void*)&Bs[0][l15 * 40 + lg * 8];
        f16x8 bl = *(const f16x8*)(const void*)&Bs[1][l15 * 40 + lg * 8];
#pragma unroll
        for (int mtl = 0; mtl < 2; ++mtl) {
            int m = w * 32 + mtl * 16 + l15;
            f16x8 ah = *(const f16x8*)(const void*)&As[0][m * 40 + lg * 8];
            f16x8 al = *(const f16x8*)(const void*)&As[1][m * 40 + lg * 8];
            acc[mtl] = __builtin_amdgcn_mfma_f32_16x16x32_f16(ah, bh, acc[mtl], 0, 0, 0);
            acc[mtl] = __builtin_amdgcn_mfma_f32_16x16x32_f16(ah, bl, acc[mtl], 0, 0, 0);
            acc[mtl] = __builtin_amdgcn_mfma_f32_16x16x32_f16(al, bh, acc[mtl], 0, 0, 0);
        }
    }
#pragma unroll
    for (int mtl = 0; mtl < 2; ++mtl)
#pragma unroll
        for (int r = 0; r < 4; ++r) {
            int m = w * 32 + mtl * 16 + lg * 4 + r;
            int n = nt * 16 + l15;
            part[((size_t)ks * 128 + m) * 144 + n] = acc[mtl][r];
        }
}

__global__ __launch_bounds__(256) void fc_reduce(
    const float* __restrict__ part, const float* __restrict__ bias,
    float* __restrict__ costs)
{
    int idx = blockIdx.x * 256 + threadIdx.x;
    if (idx >= 128 * 144) return;
    float sum = bias[idx % 144];
    for (int s = 0; s < FC_KSPLIT; ++s) sum += part[(size_t)s * (128 * 144) + idx];
    costs[idx] = sum;
}

// ---------------------------------------------------------------------------
// Bellman-Ford (144 iters) + greedy backtrack (unchanged, proven)
// ---------------------------------------------------------------------------
__global__ __launch_bounds__(192) void shortest_path(
    const float* __restrict__ costs, float* __restrict__ out)
{
    __shared__ float dA[144], dB[144], cs[144], mask[144];
    const int b = blockIdx.x, tid = threadIdx.x;
    if (tid < 144) {
        float c = costs[b * 144 + tid];
        cs[tid] = c;
        dA[tid] = (tid == 0) ? c : BIGF;
        mask[tid] = 0.f;
    }
    __syncthreads();
    float* cur = dA; float* nxt = dB;
    for (int it = 0; it < 144; ++it) {
        if (tid < 144) {
            int i = tid / 12, j = tid % 12;
            float up = (i > 0)  ? cur[tid - 12] : BIGF;
            float dn = (i < 11) ? cur[tid + 12] : BIGF;
            float lf = (j > 0)  ? cur[tid - 1]  : BIGF;
            float rt = (j < 11) ? cur[tid + 1]  : BIGF;
            float nb = fminf(fminf(up, dn), fminf(lf, rt));
            nxt[tid] = fminf(cur[tid], nb + cs[tid]);
        }
        __syncthreads();
        float* tp = cur; cur = nxt; nxt = tp;
    }
    if (tid == 0) {
        int i = 11, j = 11;
        const int di[4] = {-1, 1, 0, 0};
        const int dj[4] = {0, 0, -1, 1};
        for (int it = 0; it < 144; ++it) {
            mask[i * 12 + j] = 1.f;
            float vals[4];
#pragma unroll
            for (int k = 0; k < 4; ++k) {
                int ni = i + di[k], nj = j + dj[k];
                bool valid = (ni >= 0) && (ni < 12) && (nj >= 0) && (nj < 12);
                vals[k] = valid ? cur[ni * 12 + nj] : BIGF;
            }
            float best = vals[0]; int kb = 0;
#pragma unroll
            for (int k = 1; k < 4; ++k)
                if (vals[k] < best) { best = vals[k]; kb = k; }
            if (!(i == 0 && j == 0)) { i += di[kb]; j += dj[kb]; }
        }
    }
    __syncthreads();
    if (tid < 144) out[b * 144 + tid] = mask[tid];
}

// ---------------------------------------------------------------------------
extern "C" void kernel_launch(void* const* d_in, const int* in_sizes, int n_in,
                              void* d_out, int out_size, void* d_ws, size_t ws_size,
                              hipStream_t stream) {
    const float* x    = (const float*)d_in[0];
    const float* c1w  = (const float*)d_in[1];
    const float* bn1g = (const float*)d_in[2];
    const float* bn1b = (const float*)d_in[3];
    const float* bn1m = (const float*)d_in[4];
    const float* bn1v = (const float*)d_in[5];
    const float* blkw = (const float*)d_in[6];
    const float* blkg = (const float*)d_in[7];
    const float* blkb = (const float*)d_in[8];
    const float* blkm = (const float*)d_in[9];
    const float* blkv = (const float*)d_in[10];
    const float* fcw  = (const float*)d_in[11];
    const float* fcb  = (const float*)d_in[12];
    float* out = (float*)d_out;
    char* ws = (char*)d_ws;

    const size_t APL = 9437184;            // 128*36864 halves * 2B
    f16* a0h = (f16*)(ws);
    f16* a0l = (f16*)(ws + APL);
    f16* a1h = (f16*)(ws + 2 * APL);
    f16* a1l = (f16*)(ws + 3 * APL);
    f16* a2h = (f16*)(ws + 4 * APL);
    f16* a2l = (f16*)(ws + 5 * APL);
    float* costs = (float*)(ws + 6 * APL);                 // 73728 B
    float* part  = (float*)(ws + 6 * APL + 73728);         // 2359296 B
    f16*   wB    = (f16*)  (ws + 6 * APL + 73728 + 2359296);       // 589824 B
    float* wp1   = (float*)(ws + 6 * APL + 73728 + 2359296 + 589824);  // 37632 B
    float* b3    = (float*)(ws + 6 * APL + 73728 + 2359296 + 589824 + 37632);
    float* b1    = (float*)(ws + 6 * APL + 73728 + 2359296 + 589824 + 37632 + 1024);

    prepack<<<dim3(614), dim3(256), 0, stream>>>(
        c1w, bn1g, bn1b, bn1m, bn1v, blkw, blkg, blkb, blkm, blkv,
        wB, wp1, b3, b1);

    conv1_pool<<<dim3(1024), dim3(576), 0, stream>>>(x, wp1, b1, a0h, a0l);

    // per-layer frag stride = 9 taps * 4 nt * 2 kf * 2 hl * 512 = 73728 halves
    conv3_mfma<0, 0><<<dim3(3, 128), dim3(256), 0, stream>>>(
        a0h, a0l, wB + 0 * 73728, b3 + 0,   nullptr, nullptr, a1h, a1l);
    conv3_mfma<1, 0><<<dim3(3, 128), dim3(256), 0, stream>>>(
        a1h, a1l, wB + 1 * 73728, b3 + 64,  a0h, a0l, a2h, a2l);
    conv3_mfma<0, 0><<<dim3(3, 128), dim3(256), 0, stream>>>(
        a2h, a2l, wB + 2 * 73728, b3 + 128, nullptr, nullptr, a1h, a1l);
    conv3_mfma<1, 1><<<dim3(3, 128), dim3(256), 0, stream>>>(
        a1h, a1l, wB + 3 * 73728, b3 + 192, a2h, a2l, a0h, a0l);  // NCHW-T out

    fc_mfma<<<dim3(9, FC_KSPLIT), dim3(256), 0, stream>>>(a0h, a0l, fcw, part);
    fc_reduce<<<dim3(72), dim3(256), 0, stream>>>(part, fcb, costs);
    shortest_path<<<dim3(128), dim3(192), 0, stream>>>(costs, out);
}

// Round 6
// 285.976 us; speedup vs baseline: 3.2324x; 1.1433x over previous
//
#include <hip/hip_runtime.h>
#include <math.h>

#define BIGF 1e10f
#define EPSF 1e-5f

typedef _Float16 f16;
typedef f16 f16x8 __attribute__((ext_vector_type(8)));
typedef float f32x4 __attribute__((ext_vector_type(4)));

static __device__ __forceinline__ f16x8 mk8(uint a, uint b, uint c, uint d) {
    union { uint u[4]; f16x8 v; } t;
    t.u[0] = a; t.u[1] = b; t.u[2] = c; t.u[3] = d;
    return t.v;
}

// ---------------------------------------------------------------------------
// Prepack: fold BN; conv3 B-frags [layer4][tap9][nt4][kf2][hl2][512],
// conv1 B-frags [kh7][nt4][hl2][512] (k = ic*8+kw, ic>=3 / kw==7 -> 0),
// biases b3[256], b1[64].
// ---------------------------------------------------------------------------
__global__ __launch_bounds__(256) void prepack(
    const float* __restrict__ c1w,
    const float* __restrict__ bn1g, const float* __restrict__ bn1b,
    const float* __restrict__ bn1m, const float* __restrict__ bn1v,
    const float* __restrict__ blkw,
    const float* __restrict__ blkg, const float* __restrict__ blkb,
    const float* __restrict__ blkm, const float* __restrict__ blkv,
    f16* __restrict__ wB, f16* __restrict__ wB1,
    float* __restrict__ b3, float* __restrict__ b1)
{
    int idx = blockIdx.x * 256 + threadIdx.x;
    if (idx < 147456) {                    // conv3 weight frags
        int pos = idx;
        int j    = pos & 7;
        int lane = (pos >> 3) & 63;
        int rest = pos >> 9;               // (((layer*9+tap)*4+nt)*2+kf)
        int kf   = rest & 1;
        int r2   = rest >> 1;
        int ntl  = r2 & 3;
        int r3   = r2 >> 2;
        int tap  = r3 % 9;
        int layer= r3 / 9;
        int ic = kf * 32 + (lane >> 4) * 8 + j;
        int oc = ntl * 16 + (lane & 15);
        float s = blkg[layer * 64 + oc] * rsqrtf(blkv[layer * 64 + oc] + EPSF);
        float wv = blkw[(((size_t)layer * 64 + oc) * 64 + ic) * 9 + tap] * s;
        f16 h = (f16)wv;
        f16 lo = (f16)(wv - (float)h);
        int low9 = pos & 511;
        wB[(size_t)rest * 1024 + low9]       = h;
        wB[(size_t)rest * 1024 + 512 + low9] = lo;
    }
    int q = idx - 147456;
    if (q >= 0 && q < 28672) {             // conv1 frags
        int j = q & 7, lane = (q >> 3) & 63, rest = q >> 9;  // ((kh*4+nt)*2+hl)
        int hl = rest & 1, nt = (rest >> 1) & 3, kh = rest >> 3;
        int oc = nt * 16 + (lane & 15), lgq = lane >> 4;
        float v = 0.f;
        if (lgq < 3 && j < 7) {
            float s = bn1g[oc] * rsqrtf(bn1v[oc] + EPSF);
            v = c1w[((oc * 3 + lgq) * 7 + kh) * 7 + j] * s;
        }
        f16 h = (f16)v;
        wB1[q] = hl ? (f16)(v - (float)h) : h;
    }
    int k = idx - 147456 - 28672;
    if (k >= 0 && k < 256) {
        float s = blkg[k] * rsqrtf(blkv[k] + EPSF);
        b3[k] = blkb[k] - blkm[k] * s;
    }
    int l = idx - 147456 - 28672 - 256;
    if (l >= 0 && l < 64) {
        float s = bn1g[l] * rsqrtf(bn1v[l] + EPSF);
        b1[l] = bn1b[l] - bn1m[l] * s;
    }
}

// ---------------------------------------------------------------------------
// conv1 7x7 s2 p3 + foldedBN + ReLU + maxpool via f16-split MFMA.
// Grid (6 pool-row-groups, 128 images), 256 thr (4 waves, wave = N-tile).
// Per block: conv rows 8g-1..8g+7 (9 rows x 48 cols = 27 M-tiles),
// pool rows 4g..4g+3. Per kh: one 32-K MFMA pass (k = ic*8+kw, 21 live).
// A from raw LDS planes (b32 reads, no im2col). Pool via wave-private
// LDS plane, two wave-pairs phased.
// ---------------------------------------------------------------------------
__global__ __launch_bounds__(256) void conv1_mfma(
    const float* __restrict__ x, const f16* __restrict__ wB1,
    const float* __restrict__ bias,
    f16* __restrict__ outh, f16* __restrict__ outl)
{
    __shared__ char lds[56448];
    const int g = blockIdx.x, b = blockIdx.y;
    const int tid = threadIdx.x;
    const int w = tid >> 6, l = tid & 63;
    const int l15 = l & 15, lg = l >> 4;

    // ---- stage input rows 16g-5..16g+17 as f16 h/l planes [3][23][104] ----
    for (int i = tid; i < 7176; i += 256) ((uint*)lds)[i] = 0u;
    __syncthreads();
    const int ir0 = 16 * g - 5;
    const float* xb = x + (size_t)b * 27648;
    for (int e = tid; e < 6624; e += 256) {
        int ic = e / 2208, rem = e - ic * 2208;
        int lr = rem / 96, col = rem - lr * 96;
        int ir = ir0 + lr;
        if ((unsigned)ir < 96u) {
            float v = xb[ic * 9216 + ir * 96 + col];
            f16 h = (f16)v;
            f16 lo = (f16)(v - (float)h);
            int hoff = ic * 4784 + lr * 208 + (col + 3) * 2;
            *(f16*)(lds + hoff) = h;
            *(f16*)(lds + 14352 + hoff) = lo;
        }
    }
    __syncthreads();

    // ---- MFMA main: 7 kh passes x 27 M-tiles x 3 split-passes ----
    f32x4 acc[9][3];
#pragma unroll
    for (int rb = 0; rb < 9; ++rb)
#pragma unroll
        for (int cb = 0; cb < 3; ++cb) acc[rb][cb] = (f32x4){0.f, 0.f, 0.f, 0.f};

    const int icB = (lg >= 3 ? 0 : lg) * 4784;
    const f16* wq = wB1 + (size_t)w * 1024 + (size_t)l * 8;

    f16x8 bh = *(const f16x8*)(const void*)(wq);
    f16x8 bl = *(const f16x8*)(const void*)(wq + 512);
#pragma unroll 1
    for (int kh = 0; kh < 7; ++kh) {
        f16x8 bhn = bh, bln = bl;
        if (kh < 6) {
            bhn = *(const f16x8*)(const void*)(wq + (kh + 1) * 4096);
            bln = *(const f16x8*)(const void*)(wq + (kh + 1) * 4096 + 512);
        }
#pragma unroll
        for (int rb = 0; rb < 9; ++rb) {
            const char* rowp = lds + icB + (2 * rb + kh) * 208;
#pragma unroll
            for (int cb = 0; cb < 3; ++cb) {
                int aoff = 4 * (cb * 16 + l15);
                const uint* ph = (const uint*)(rowp + aoff);
                const uint* pl = (const uint*)(rowp + 14352 + aoff);
                f16x8 ah = mk8(ph[0], ph[1], ph[2], ph[3]);
                f16x8 al = mk8(pl[0], pl[1], pl[2], pl[3]);
                acc[rb][cb] = __builtin_amdgcn_mfma_f32_16x16x32_f16(ah, bh, acc[rb][cb], 0, 0, 0);
                acc[rb][cb] = __builtin_amdgcn_mfma_f32_16x16x32_f16(ah, bl, acc[rb][cb], 0, 0, 0);
                acc[rb][cb] = __builtin_amdgcn_mfma_f32_16x16x32_f16(al, bh, acc[rb][cb], 0, 0, 0);
            }
        }
        bh = bhn; bl = bln;
    }

    // ---- epilogue: bias+relu -> wave LDS plane [16 oc][441], pool 3x3 s2 ----
    const float bi = bias[w * 16 + l15];
    float* pbuf = (float*)(void*)lds + (size_t)(w & 1) * 7056;  // 16*441 dwords

    __syncthreads();   // input planes dead, all MFMA done
#pragma unroll 1
    for (int phase = 0; phase < 2; ++phase) {
        if ((w >> 1) == phase) {
#pragma unroll
            for (int rb = 0; rb < 9; ++rb)
#pragma unroll
                for (int cb = 0; cb < 3; ++cb)
#pragma unroll
                    for (int r = 0; r < 4; ++r) {
                        int col = cb * 16 + lg * 4 + r;
                        pbuf[l15 * 441 + rb * 49 + col] =
                            fmaxf(acc[rb][cb][r] + bi, 0.f);
                    }
        }
        __syncthreads();
        if ((w >> 1) == phase) {
#pragma unroll 1
            for (int i = 0; i < 24; ++i) {
                int ppc = i * 4 + lg;              // 0..95
                int pr = ppc / 24, pc = ppc % 24;
                float m = -INFINITY;
#pragma unroll
                for (int kr = 0; kr < 3; ++kr) {
                    int lrr = 2 * pr + kr;
                    if (8 * g - 1 + lrr < 0) continue;   // conv row -1 (g=0)
#pragma unroll
                    for (int kc = 0; kc < 3; ++kc) {
                        int cc = 2 * pc - 1 + kc;
                        if ((unsigned)cc < 48u)
                            m = fmaxf(m, pbuf[l15 * 441 + lrr * 49 + cc]);
                    }
                }
                f16 h = (f16)m;
                f16 lo = (f16)(m - (float)h);
                size_t off = (size_t)b * 36864 +
                             (size_t)((4 * g + pr) * 24 + pc) * 64 + w * 16 + l15;
                outh[off] = h;
                outl[off] = lo;
            }
        }
        __syncthreads();
    }
}

// ---------------------------------------------------------------------------
// conv3x3 s1 p1 (64->64) + foldedBN (+res) + ReLU via f16-split MFMA.
// (unchanged from R5 — verified absmax 0)
// ---------------------------------------------------------------------------
template<int MODE, int OUTT>
__global__ __launch_bounds__(256) void conv3_mfma(
    const f16* __restrict__ inh, const f16* __restrict__ inl,
    const f16* __restrict__ wB,      // this layer's frag base (73728 halves)
    const float* __restrict__ bias,  // folded [64]
    const f16* __restrict__ resh, const f16* __restrict__ resl,
    f16* __restrict__ outh, f16* __restrict__ outl)
{
    __shared__ f16 lh[10 * 26 * 64];
    __shared__ f16 ll[10 * 26 * 64];
    const int r0 = blockIdx.x * 8;
    const int b  = blockIdx.y;
    const int tid = threadIdx.x;
    const int w = tid >> 6, l = tid & 63;
    const int l15 = l & 15, lg = l >> 4;

    for (int i = tid; i < 320; i += 256) {
        int arr = i >= 160; int c2 = i - arr * 160;
        int slot = c2 & 7; int pb = c2 >> 3;
        int lr = pb >> 1; int pc = (pb & 1) ? 25 : 0;
        int pix = lr * 26 + pc;
        int off = (pix * 128 + slot * 16) ^ ((pix & 7) << 4);
        *(uint4*)((arr ? (char*)ll : (char*)lh) + off) = make_uint4(0, 0, 0, 0);
    }
#pragma unroll
    for (int i = 0; i < 15; ++i) {
        int ch = tid + i * 256;
        int arr = ch >= 1920; int c2 = ch - arr * 1920;
        int slot = c2 & 7; int pix24 = c2 >> 3;
        int lr = pix24 / 24, pc = pix24 % 24;
        int ir = r0 - 1 + lr;
        uint4 v = make_uint4(0, 0, 0, 0);
        if ((unsigned)ir < 24u) {
            const f16* src = (arr ? inl : inh) +
                (((size_t)b * 576 + ir * 24 + pc) << 6) + slot * 8;
            v = *(const uint4*)(const void*)src;
        }
        int pix = lr * 26 + pc + 1;
        int off = (pix * 128 + slot * 16) ^ ((pix & 7) << 4);
        *(uint4*)((arr ? (char*)ll : (char*)lh) + off) = v;
    }

    int pr_[3], pc_[3];
#pragma unroll
    for (int mtl = 0; mtl < 3; ++mtl) {
        int lp = (w * 3 + mtl) * 16 + l15;
        pr_[mtl] = lp / 24; pc_[mtl] = lp % 24;
    }

    f32x4 acc[3][4];
#pragma unroll
    for (int m = 0; m < 3; ++m)
#pragma unroll
        for (int n = 0; n < 4; ++n) acc[m][n] = (f32x4){0.f, 0.f, 0.f, 0.f};

    __syncthreads();

#pragma unroll 1
    for (int tap = 0; tap < 9; ++tap) {
        int dr = tap / 3, dc = tap % 3;
#pragma unroll
        for (int kf = 0; kf < 2; ++kf) {
            const f16* wb = wB + (size_t)tap * 8192 + (size_t)kf * 1024 + (size_t)l * 8;
            f16x8 bh[4], bl[4];
#pragma unroll
            for (int nt = 0; nt < 4; ++nt) {
                bh[nt] = *(const f16x8*)(const void*)(wb + nt * 2048);
                bl[nt] = *(const f16x8*)(const void*)(wb + nt * 2048 + 512);
            }
#pragma unroll
            for (int mtl = 0; mtl < 3; ++mtl) {
                int pix = (pr_[mtl] + dr) * 26 + (pc_[mtl] + dc);
                int off = (pix * 128 + kf * 64 + lg * 16) ^ ((pix & 7) << 4);
                f16x8 ah = *(const f16x8*)((const char*)lh + off);
                f16x8 al = *(const f16x8*)((const char*)ll + off);
#pragma unroll
                for (int nt = 0; nt < 4; ++nt) {
                    acc[mtl][nt] = __builtin_amdgcn_mfma_f32_16x16x32_f16(ah, bh[nt], acc[mtl][nt], 0, 0, 0);
                    acc[mtl][nt] = __builtin_amdgcn_mfma_f32_16x16x32_f16(ah, bl[nt], acc[mtl][nt], 0, 0, 0);
                    acc[mtl][nt] = __builtin_amdgcn_mfma_f32_16x16x32_f16(al, bh[nt], acc[mtl][nt], 0, 0, 0);
                }
            }
        }
    }

    float bi[4];
#pragma unroll
    for (int nt = 0; nt < 4; ++nt) bi[nt] = bias[nt * 16 + l15];

#pragma unroll
    for (int mtl = 0; mtl < 3; ++mtl) {
#pragma unroll
        for (int nt = 0; nt < 4; ++nt) {
#pragma unroll
            for (int r = 0; r < 4; ++r) {
                int lp = (w * 3 + mtl) * 16 + lg * 4 + r;
                int p = r0 * 24 + lp;
                int oc = nt * 16 + l15;
                float v = acc[mtl][nt][r] + bi[nt];
                if (MODE) {
                    size_t ridx = (size_t)b * 36864 + (size_t)p * 64 + oc;
                    v += (float)resh[ridx] + (float)resl[ridx];
                }
                v = fmaxf(v, 0.f);
                f16 h = (f16)v;
                f16 lo = (f16)(v - (float)h);
                size_t oidx = OUTT ? ((size_t)b * 36864 + (size_t)oc * 576 + p)
                                   : ((size_t)b * 36864 + (size_t)p * 64 + oc);
                outh[oidx] = h;
                outl[oidx] = lo;
            }
        }
    }
}

// ---------------------------------------------------------------------------
// FC via f16-split MFMA (unchanged from R5)
// ---------------------------------------------------------------------------
#define FC_KSPLIT 32

__global__ __launch_bounds__(256) void fc_mfma(
    const f16* __restrict__ Ath, const f16* __restrict__ Atl,
    const float* __restrict__ Bw, float* __restrict__ part)
{
    __shared__ f16 As[2][128 * 40];
    __shared__ f16 Bs[2][16 * 40];
    const int nt = blockIdx.x;
    const int ks = blockIdx.y;
    const int tid = threadIdx.x;
    const int w = tid >> 6, l = tid & 63;
    const int l15 = l & 15, lg = l >> 4;
    const int k0b = ks * 1152;

    f32x4 acc[2];
    acc[0] = (f32x4){0.f, 0.f, 0.f, 0.f};
    acc[1] = (f32x4){0.f, 0.f, 0.f, 0.f};

    const int bn = tid >> 4, bkl = (tid & 15) * 2;
#pragma unroll 1
    for (int st = 0; st < 36; ++st) {
        int k0 = k0b + st * 32;
        __syncthreads();
#pragma unroll
        for (int i = 0; i < 4; ++i) {
            int ch = tid + i * 256;
            int arr = ch >= 512; int c2 = ch - arr * 512;
            int m = c2 >> 2, slot = c2 & 3;
            const f16* src = (arr ? Atl : Ath) + (size_t)m * 36864 + k0 + slot * 8;
            *(uint4*)(void*)&As[arr][m * 40 + slot * 8] = *(const uint4*)(const void*)src;
        }
        {
            float2 f2 = *(const float2*)&Bw[(size_t)(nt * 16 + bn) * 36864 + k0 + bkl];
            f16 h0 = (f16)f2.x, h1 = (f16)f2.y;
            Bs[0][bn * 40 + bkl] = h0;     Bs[0][bn * 40 + bkl + 1] = h1;
            Bs[1][bn * 40 + bkl] = (f16)(f2.x - (float)h0);
            Bs[1][bn * 40 + bkl + 1] = (f16)(f2.y - (float)h1);
        }
        __syncthreads();
        f16x8 bh = *(const f16x8*)(const void*)&Bs[0][l15 * 40 + lg * 8];
        f16x8 bl = *(const f16x8*)(const void*)&Bs[1][l15 * 40 + lg * 8];
#pragma unroll
        for (int mtl = 0; mtl < 2; ++mtl) {
            int m = w * 32 + mtl * 16 + l15;
            f16x8 ah = *(const f16x8*)(const void*)&As[0][m * 40 + lg * 8];
            f16x8 al = *(const f16x8*)(const void*)&As[1][m * 40 + lg * 8];
            acc[mtl] = __builtin_amdgcn_mfma_f32_16x16x32_f16(ah, bh, acc[mtl], 0, 0, 0);
            acc[mtl] = __builtin_amdgcn_mfma_f32_16x16x32_f16(ah, bl, acc[mtl], 0, 0, 0);
            acc[mtl] = __builtin_amdgcn_mfma_f32_16x16x32_f16(al, bh, acc[mtl], 0, 0, 0);
        }
    }
#pragma unroll
    for (int mtl = 0; mtl < 2; ++mtl)
#pragma unroll
        for (int r = 0; r < 4; ++r) {
            int m = w * 32 + mtl * 16 + lg * 4 + r;
            int n = nt * 16 + l15;
            part[((size_t)ks * 128 + m) * 144 + n] = acc[mtl][r];
        }
}

__global__ __launch_bounds__(256) void fc_reduce(
    const float* __restrict__ part, const float* __restrict__ bias,
    float* __restrict__ costs)
{
    int idx = blockIdx.x * 256 + threadIdx.x;
    if (idx >= 128 * 144) return;
    float sum = bias[idx % 144];
    for (int s = 0; s < FC_KSPLIT; ++s) sum += part[(size_t)s * (128 * 144) + idx];
    costs[idx] = sum;
}

// ---------------------------------------------------------------------------
// Bellman-Ford (144 iters) + greedy backtrack (unchanged, proven)
// ---------------------------------------------------------------------------
__global__ __launch_bounds__(192) void shortest_path(
    const float* __restrict__ costs, float* __restrict__ out)
{
    __shared__ float dA[144], dB[144], cs[144], mask[144];
    const int b = blockIdx.x, tid = threadIdx.x;
    if (tid < 144) {
        float c = costs[b * 144 + tid];
        cs[tid] = c;
        dA[tid] = (tid == 0) ? c : BIGF;
        mask[tid] = 0.f;
    }
    __syncthreads();
    float* cur = dA; float* nxt = dB;
    for (int it = 0; it < 144; ++it) {
        if (tid < 144) {
            int i = tid / 12, j = tid % 12;
            float up = (i > 0)  ? cur[tid - 12] : BIGF;
            float dn = (i < 11) ? cur[tid + 12] : BIGF;
            float lf = (j > 0)  ? cur[tid - 1]  : BIGF;
            float rt = (j < 11) ? cur[tid + 1]  : BIGF;
            float nb = fminf(fminf(up, dn), fminf(lf, rt));
            nxt[tid] = fminf(cur[tid], nb + cs[tid]);
        }
        __syncthreads();
        float* tp = cur; cur = nxt; nxt = tp;
    }
    if (tid == 0) {
        int i = 11, j = 11;
        const int di[4] = {-1, 1, 0, 0};
        const int dj[4] = {0, 0, -1, 1};
        for (int it = 0; it < 144; ++it) {
            mask[i * 12 + j] = 1.f;
            float vals[4];
#pragma unroll
            for (int k = 0; k < 4; ++k) {
                int ni = i + di[k], nj = j + dj[k];
                bool valid = (ni >= 0) && (ni < 12) && (nj >= 0) && (nj < 12);
                vals[k] = valid ? cur[ni * 12 + nj] : BIGF;
            }
            float best = vals[0]; int kb = 0;
#pragma unroll
            for (int k = 1; k < 4; ++k)
                if (vals[k] < best) { best = vals[k]; kb = k; }
            if (!(i == 0 && j == 0)) { i += di[kb]; j += dj[kb]; }
        }
    }
    __syncthreads();
    if (tid < 144) out[b * 144 + tid] = mask[tid];
}

// ---------------------------------------------------------------------------
extern "C" void kernel_launch(void* const* d_in, const int* in_sizes, int n_in,
                              void* d_out, int out_size, void* d_ws, size_t ws_size,
                              hipStream_t stream) {
    const float* x    = (const float*)d_in[0];
    const float* c1w  = (const float*)d_in[1];
    const float* bn1g = (const float*)d_in[2];
    const float* bn1b = (const float*)d_in[3];
    const float* bn1m = (const float*)d_in[4];
    const float* bn1v = (const float*)d_in[5];
    const float* blkw = (const float*)d_in[6];
    const float* blkg = (const float*)d_in[7];
    const float* blkb = (const float*)d_in[8];
    const float* blkm = (const float*)d_in[9];
    const float* blkv = (const float*)d_in[10];
    const float* fcw  = (const float*)d_in[11];
    const float* fcb  = (const float*)d_in[12];
    float* out = (float*)d_out;
    char* ws = (char*)d_ws;

    const size_t APL = 9437184;            // 128*36864 halves * 2B
    f16* a0h = (f16*)(ws);
    f16* a0l = (f16*)(ws + APL);
    f16* a1h = (f16*)(ws + 2 * APL);
    f16* a1l = (f16*)(ws + 3 * APL);
    f16* a2h = (f16*)(ws + 4 * APL);
    f16* a2l = (f16*)(ws + 5 * APL);
    float* costs = (float*)(ws + 6 * APL);                       // 73728 B
    float* part  = (float*)(ws + 6 * APL + 73728);               // 2359296 B
    f16*   wB    = (f16*)  (ws + 6 * APL + 73728 + 2359296);     // 589824 B
    float* b3    = (float*)(ws + 6 * APL + 73728 + 2359296 + 589824);       // 1024 B
    float* b1    = (float*)(ws + 6 * APL + 73728 + 2359296 + 589824 + 1024);// 256 B
    f16*   wB1   = (f16*)  (ws + 6 * APL + 73728 + 2359296 + 589824 + 1280);// 57344 B

    prepack<<<dim3(690), dim3(256), 0, stream>>>(
        c1w, bn1g, bn1b, bn1m, bn1v, blkw, blkg, blkb, blkm, blkv,
        wB, wB1, b3, b1);

    conv1_mfma<<<dim3(6, 128), dim3(256), 0, stream>>>(x, wB1, b1, a0h, a0l);

    // per-layer frag stride = 9 taps * 4 nt * 2 kf * 2 hl * 512 = 73728 halves
    conv3_mfma<0, 0><<<dim3(3, 128), dim3(256), 0, stream>>>(
        a0h, a0l, wB + 0 * 73728, b3 + 0,   nullptr, nullptr, a1h, a1l);
    conv3_mfma<1, 0><<<dim3(3, 128), dim3(256), 0, stream>>>(
        a1h, a1l, wB + 1 * 73728, b3 + 64,  a0h, a0l, a2h, a2l);
    conv3_mfma<0, 0><<<dim3(3, 128), dim3(256), 0, stream>>>(
        a2h, a2l, wB + 2 * 73728, b3 + 128, nullptr, nullptr, a1h, a1l);
    conv3_mfma<1, 1><<<dim3(3, 128), dim3(256), 0, stream>>>(
        a1h, a1l, wB + 3 * 73728, b3 + 192, a2h, a2l, a0h, a0l);  // NCHW-T out

    fc_mfma<<<dim3(9, FC_KSPLIT), dim3(256), 0, stream>>>(a0h, a0l, fcw, part);
    fc_reduce<<<dim3(72), dim3(256), 0, stream>>>(part, fcb, costs);
    shortest_path<<<dim3(128), dim3(192), 0, stream>>>(costs, out);
}